// Round 3
// baseline (381.516 us; speedup 1.0000x reference)
//
#include <hip/hip_runtime.h>

// HMM forward scan, one workgroup per unit u. U=256, N=64, S=4, B=64, T=1024.
// Wave w owns batches [16w,16w+16); lane (q=lane>>4,l=lane&15) owns batch
// b=16w+l and the 16 states j = sig(jt, 4q+r).
//
// R11 = R10 (unnormalized recursion, exact pow2 octet rescale, octet loop
// not unrolled) with the cross-lane ss reduction replaced by an MFMA
// ones-row matvec:
//   ss = mfma(ones, bf1, mfma(ones, bf0, 0))[0]
// Every lane gets its batch's full 64-state sum directly -> no ds_swizzle,
// no lgkmcnt stall, no consume pipeline, no pp0/pa* registers. ss is now
// sum_j bf16(gv_j) (the same rounded values the R-matvec consumes).
// Step restructured into V phase (VALU: gv muls, bf16 packs, be pack,
// prev-ss capture) then M phase (14 MFMAs: R x8, S x2, E x4) so the wave
// issues V(t+1) while M(t) still occupies the matrix pipe.
// x is prefetched into RAW float registers (cvt at use, not at load), so
// no cvt chains onto the loads' vmcnt.

#define U_ 256
#define N_ 64
#define S_ 4
#define B_ 64
#define T_ 1024
#define ROWP 72
#define LN2F 0.69314718055994530942f

typedef __attribute__((ext_vector_type(8))) __bf16 bf16x8;
typedef __attribute__((ext_vector_type(4))) float floatx4;

__device__ __forceinline__ int sig(int jt, int m) {
    return 32 * (jt >> 1) + 4 * (jt & 1) + 8 * (m >> 2) + (m & 3);
}

__launch_bounds__(256, 1)
__global__ void hmm_fwd_kernel(const float* __restrict__ xg,     // [B][T][S]
                               const float* __restrict__ trans,  // [U][N][N]
                               const float* __restrict__ emis,   // [U][N][S]
                               const float* __restrict__ initk,  // [U][N]
                               float* __restrict__ out)          // [B][T][U]
{
    __shared__ __bf16 AT[N_ * ROWP];
    __shared__ float BemS[N_][S_];
    __shared__ float IS[N_];

    const int bid = blockIdx.x;
    const int u = ((bid & 7) << 5) | (bid >> 3);   // XCD-aware u swizzle
    const int tid = threadIdx.x;
    const int lane = tid & 63;
    const int w = tid >> 6;
    const int q = lane >> 4;
    const int l = lane & 15;

    // ---------------- prologue: softmaxes (one-time) ----------------
    if (tid < 64) {
        const float* rowp = trans + (u * N_ + tid) * N_;
        float v[N_];
        #pragma unroll
        for (int k = 0; k < 16; ++k) {
            floatx4 t4 = *(const floatx4*)(rowp + 4 * k);
            v[4*k] = t4.x; v[4*k+1] = t4.y; v[4*k+2] = t4.z; v[4*k+3] = t4.w;
        }
        float m = v[0];
        #pragma unroll
        for (int j = 1; j < N_; ++j) m = fmaxf(m, v[j]);
        float s = 0.f;
        #pragma unroll
        for (int j = 0; j < N_; ++j) { v[j] = __expf(v[j] - m); s += v[j]; }
        float inv = 1.0f / s;
        #pragma unroll
        for (int j = 0; j < N_; ++j) AT[j * ROWP + tid] = (__bf16)(v[j] * inv);
    } else if (tid < 128) {
        int n = tid - 64;
        floatx4 e4 = *(const floatx4*)(emis + (u * N_ + n) * S_);
        float m = fmaxf(fmaxf(e4.x, e4.y), fmaxf(e4.z, e4.w));
        float a = __expf(e4.x - m), b2 = __expf(e4.y - m);
        float c = __expf(e4.z - m), d = __expf(e4.w - m);
        float inv = 1.0f / (a + b2 + c + d);
        BemS[n][0] = a*inv; BemS[n][1] = b2*inv; BemS[n][2] = c*inv; BemS[n][3] = d*inv;
    } else if (tid < 192) {
        int j = tid - 128;
        float v = initk[u * N_ + j];
        float m = v;
        #pragma unroll
        for (int s = 1; s < 64; s <<= 1) m = fmaxf(m, __shfl_xor(m, s, 64));
        float e = __expf(v - m);
        float ssum = e;
        #pragma unroll
        for (int s = 1; s < 64; s <<= 1) ssum += __shfl_xor(ssum, s, 64);
        IS[j] = e / ssum;
    }
    __syncthreads();

    // ------------- persistent register state -------------
    bf16x8 afrag[4][2];
    #pragma unroll
    for (int jt = 0; jt < 4; ++jt)
        #pragma unroll
        for (int kt = 0; kt < 2; ++kt)
            afrag[jt][kt] = *(const bf16x8*)&AT[sig(jt, l) * ROWP + 32*kt + 8*q];

    bf16x8 afragE[4];
    #pragma unroll
    for (int jt = 0; jt < 4; ++jt) {
        #pragma unroll
        for (int p = 0; p < 8; ++p) afragE[jt][p] = (__bf16)0.f;
        if (q == 0) {
            #pragma unroll
            for (int c = 0; c < 4; ++c)
                afragE[jt][c] = (__bf16)BemS[sig(jt, l)][c];
        }
    }

    bf16x8 onesf;
    #pragma unroll
    for (int p = 0; p < 8; ++p) onesf[p] = (__bf16)1.0f;

    floatx4 Rv[4];
    #pragma unroll
    for (int jt = 0; jt < 4; ++jt)
        #pragma unroll
        for (int r = 0; r < 4; ++r) Rv[jt][r] = IS[sig(jt, 4*q + r)];

    __asm__ volatile("" ::: "memory");   // pin LDS-sourced state in VGPRs

    const int b = 16*w + l;
    const float* xin = xg + b * (T_ * S_);
    float* llout = out + (size_t)b * T_ * U_ + u;

    const floatx4 z = {0.f, 0.f, 0.f, 0.f};
    floatx4 Ev[4];
    floatx4 ssv = z;                     // prev step's ss-MFMA result

    // ---------------- pipeline fill ----------------
    {
        floatx4 x0 = *(const floatx4*)xin;
        bf16x8 be0;
        be0[0] = (__bf16)x0.x; be0[1] = (__bf16)x0.y;
        be0[2] = (__bf16)x0.z; be0[3] = (__bf16)x0.w;
        be0[4] = (__bf16)0.f;  be0[5] = (__bf16)0.f;
        be0[6] = (__bf16)0.f;  be0[7] = (__bf16)0.f;
        #pragma unroll
        for (int jt = 0; jt < 4; ++jt)
            Ev[jt] = __builtin_amdgcn_mfma_f32_16x16x32_bf16(afragE[jt], be0, z, 0, 0, 0);
    }
    floatx4 xvA[4], xvB[4];
    #pragma unroll
    for (int i = 0; i < 4; ++i)
        xvA[i] = *(const floatx4*)(xin + (1 + i) * S_);   // x_1..x_4 raw

    float hist[8];
    float ssf = 1.0f;
    float Cacc = 0.f;
    float offacc = 0.f, sumk = 0.f;

    // one HMM step. xr = raw x_{t+1}.
    auto step = [&](const floatx4& xr, int slot, bool own, bool ownP) {
        // ---------- V phase (VALU only) ----------
        floatx4 gv[4];
        #pragma unroll
        for (int jt = 0; jt < 4; ++jt) gv[jt] = Ev[jt] * Rv[jt];

        bf16x8 bf0, bf1;
        #pragma unroll
        for (int p = 0; p < 4; ++p) {
            bf0[p]     = (__bf16)gv[0][p];
            bf0[4 + p] = (__bf16)gv[1][p];
            bf1[p]     = (__bf16)gv[2][p];
            bf1[4 + p] = (__bf16)gv[3][p];
        }

        bf16x8 be;
        be[0] = (__bf16)xr.x; be[1] = (__bf16)xr.y;
        be[2] = (__bf16)xr.z; be[3] = (__bf16)xr.w;
        be[4] = (__bf16)0.f;  be[5] = (__bf16)0.f;
        be[6] = (__bf16)0.f;  be[7] = (__bf16)0.f;

        // capture previous step's ss (ss identical across q for same l)
        {
            float ssp = ssv[0];
            if (slot == 0) {
                hist[7] = ownP ? ssp : hist[7];
            } else {
                hist[slot - 1] = own ? ssp : hist[slot - 1];
                if (slot == 6) ssf = ssp;   // slot-5 ss, 2 steps of slack
            }
        }

        // ---------- M phase (14 MFMAs) ----------
        // R_{t+1} = A^T b_t (chained C accumulation)
        #pragma unroll
        for (int jt = 0; jt < 4; ++jt) {
            floatx4 acc = __builtin_amdgcn_mfma_f32_16x16x32_bf16(afrag[jt][0], bf0, z, 0, 0, 0);
            Rv[jt] = __builtin_amdgcn_mfma_f32_16x16x32_bf16(afrag[jt][1], bf1, acc, 0, 0, 0);
        }
        // ss_t = 1^T b_t  (every lane gets its batch's full sum)
        {
            floatx4 sa = __builtin_amdgcn_mfma_f32_16x16x32_bf16(onesf, bf0, z, 0, 0, 0);
            ssv = __builtin_amdgcn_mfma_f32_16x16x32_bf16(onesf, bf1, sa, 0, 0, 0);
        }
        // Ev_{t+1} = B * x_{t+1}
        #pragma unroll
        for (int jt = 0; jt < 4; ++jt)
            Ev[jt] = __builtin_amdgcn_mfma_f32_16x16x32_bf16(afragE[jt], be, z, 0, 0, 0);
    };

    // ---------------- T-loop: one octet per iteration ----------------
    #pragma unroll 1
    for (int tb = 0; tb < T_; tb += 8) {
        const int oct = (tb >> 3) & 3;
        const bool own  = (q == oct);
        const bool ownP = (q == ((oct + 3) & 3));

        #pragma unroll
        for (int i = 0; i < 4; ++i) {
            int ti = tb + 5 + i; ti = (ti < T_) ? ti : T_ - 1;
            xvB[i] = *(const floatx4*)(xin + ti * S_);
        }

        step(xvA[0], 0, own, ownP); step(xvA[1], 1, own, ownP);
        step(xvA[2], 2, own, ownP); step(xvA[3], 3, own, ownP);

        #pragma unroll
        for (int i = 0; i < 4; ++i) {
            int ti = tb + 9 + i; ti = (ti < T_) ? ti : T_ - 1;
            xvA[i] = *(const floatx4*)(xin + ti * S_);
        }

        step(xvB[0], 4, own, ownP); step(xvB[1], 5, own, ownP);
        step(xvB[2], 6, own, ownP); step(xvB[3], 7, own, ownP);

        // octet boundary: exact power-of-2 rescale of the hat-state.
        // f = 2^-k, k = unbiased exponent of ssraw_{slot5} (2-step slack).
        {
            unsigned eb = (__float_as_uint(ssf) >> 23) & 255u;
            float f = __uint_as_float((254u - eb) << 23);
            #pragma unroll
            for (int jt = 0; jt < 4; ++jt) Rv[jt] *= f;
            float kf = (float)((int)eb - 127);
            offacc += (q > oct) ? kf : 0.f;   // octets before lane q's octet
            sumk   += kf;
        }

        // ---------------- flush: ll_t = log(ssraw_t) + correction -------
        if (oct == 3) {
            {   // capture slot 7's ss (issued 4 MFMA-slots ago)
                float ssp = ssv[0];
                hist[7] = own ? ssp : hist[7];
            }
            float base = Cacc + LN2F * offacc;
            float* fp = llout + (size_t)(tb - 24 + 8 * q) * U_;
            #pragma unroll
            for (int k = 0; k < 8; ++k)
                fp[(size_t)k * U_] = __logf(hist[k]) + base;
            Cacc += LN2F * sumk;
            offacc = 0.f; sumk = 0.f;
        }
    }
}

extern "C" void kernel_launch(void* const* d_in, const int* in_sizes, int n_in,
                              void* d_out, int out_size, void* d_ws, size_t ws_size,
                              hipStream_t stream) {
    const float* xg    = (const float*)d_in[0];
    const float* trans = (const float*)d_in[1];
    const float* emis  = (const float*)d_in[2];
    const float* initk = (const float*)d_in[3];
    float* out = (float*)d_out;
    hipLaunchKernelGGL(hmm_fwd_kernel, dim3(U_), dim3(256), 0, stream,
                       xg, trans, emis, initk, out);
}

// Round 4
// 364.720 us; speedup vs baseline: 1.0461x; 1.0461x over previous
//
#include <hip/hip_runtime.h>

// HMM forward scan, one workgroup per unit u. U=256, N=64, S=4, B=64, T=1024.
// Wave w owns batches [16w,16w+16); lane (q=lane>>4,l=lane&15) owns batch
// b=16w+l and the 16 states j = sig(jt, 4q+r).
//
// R12: MFMA-count reduction. Evidence (R8 vs R11): time is invariant at
// ~332us across 12-vs-14 MFMA/step with completely different ss paths;
// per-step spacing ~55 cy/MFMA with the pipe 70% idle. Model: a single
// wave (we are pinned at 1 wave/SIMD: 1024 chains / 1024 SIMDs) cannot
// pipeline its own MFMA stream (cf. m233: MFMA-only = 86% peak only with
// 2 waves/SIMD); period ~= N_mfma * ~50cy. So: cut N_mfma 14 -> 8.
//  - E-MFMAs (4) removed: E_t = Bem . x_t is K=4, independent of the
//    recurrence, computed on the VALU (16 dot4 = 64 FMA/step) from f32
//    coefficients cBem[4][4] (floatx4 each) held in registers. VALU
//    issues inside the forced MFMA gaps -> nearly free.
//  - ss-MFMAs (2) removed: ss via in-lane adds + 3 shfl_xor (R10's
//    proven path: raw ss captured lag-1, no in-loop consumer except the
//    once-per-octet exponent read).
//  - R stays 8x chained bf16 16x16x32 (the bf16 floor).
// Unnormalized recursion + exact pow2 octet rescale + once-per-32 flush
// unchanged from R10.

#define U_ 256
#define N_ 64
#define S_ 4
#define B_ 64
#define T_ 1024
#define ROWP 72
#define LN2F 0.69314718055994530942f

typedef __attribute__((ext_vector_type(8))) __bf16 bf16x8;
typedef __attribute__((ext_vector_type(4))) float floatx4;

__device__ __forceinline__ int sig(int jt, int m) {
    return 32 * (jt >> 1) + 4 * (jt & 1) + 8 * (m >> 2) + (m & 3);
}

__launch_bounds__(256, 1)
__global__ void hmm_fwd_kernel(const float* __restrict__ xg,     // [B][T][S]
                               const float* __restrict__ trans,  // [U][N][N]
                               const float* __restrict__ emis,   // [U][N][S]
                               const float* __restrict__ initk,  // [U][N]
                               float* __restrict__ out)          // [B][T][U]
{
    __shared__ __bf16 AT[N_ * ROWP];
    __shared__ float BemS[N_][S_];
    __shared__ float IS[N_];

    const int bid = blockIdx.x;
    const int u = ((bid & 7) << 5) | (bid >> 3);   // XCD-aware u swizzle
    const int tid = threadIdx.x;
    const int lane = tid & 63;
    const int w = tid >> 6;
    const int q = lane >> 4;
    const int l = lane & 15;

    // ---------------- prologue: softmaxes (one-time) ----------------
    if (tid < 64) {
        const float* rowp = trans + (u * N_ + tid) * N_;
        float v[N_];
        #pragma unroll
        for (int k = 0; k < 16; ++k) {
            floatx4 t4 = *(const floatx4*)(rowp + 4 * k);
            v[4*k] = t4.x; v[4*k+1] = t4.y; v[4*k+2] = t4.z; v[4*k+3] = t4.w;
        }
        float m = v[0];
        #pragma unroll
        for (int j = 1; j < N_; ++j) m = fmaxf(m, v[j]);
        float s = 0.f;
        #pragma unroll
        for (int j = 0; j < N_; ++j) { v[j] = __expf(v[j] - m); s += v[j]; }
        float inv = 1.0f / s;
        #pragma unroll
        for (int j = 0; j < N_; ++j) AT[j * ROWP + tid] = (__bf16)(v[j] * inv);
    } else if (tid < 128) {
        int n = tid - 64;
        floatx4 e4 = *(const floatx4*)(emis + (u * N_ + n) * S_);
        float m = fmaxf(fmaxf(e4.x, e4.y), fmaxf(e4.z, e4.w));
        float a = __expf(e4.x - m), b2 = __expf(e4.y - m);
        float c = __expf(e4.z - m), d = __expf(e4.w - m);
        float inv = 1.0f / (a + b2 + c + d);
        BemS[n][0] = a*inv; BemS[n][1] = b2*inv; BemS[n][2] = c*inv; BemS[n][3] = d*inv;
    } else if (tid < 192) {
        int j = tid - 128;
        float v = initk[u * N_ + j];
        float m = v;
        #pragma unroll
        for (int s = 1; s < 64; s <<= 1) m = fmaxf(m, __shfl_xor(m, s, 64));
        float e = __expf(v - m);
        float ssum = e;
        #pragma unroll
        for (int s = 1; s < 64; s <<= 1) ssum += __shfl_xor(ssum, s, 64);
        IS[j] = e / ssum;
    }
    __syncthreads();

    // ------------- persistent register state -------------
    bf16x8 afrag[4][2];
    #pragma unroll
    for (int jt = 0; jt < 4; ++jt)
        #pragma unroll
        for (int kt = 0; kt < 2; ++kt)
            afrag[jt][kt] = *(const bf16x8*)&AT[sig(jt, l) * ROWP + 32*kt + 8*q];

    // f32 emission coefficients, one floatx4 per owned state
    floatx4 cBem[4][4];
    #pragma unroll
    for (int jt = 0; jt < 4; ++jt)
        #pragma unroll
        for (int r = 0; r < 4; ++r)
            cBem[jt][r] = *(const floatx4*)&BemS[sig(jt, 4*q + r)][0];

    floatx4 Rv[4];
    #pragma unroll
    for (int jt = 0; jt < 4; ++jt)
        #pragma unroll
        for (int r = 0; r < 4; ++r) Rv[jt][r] = IS[sig(jt, 4*q + r)];

    __asm__ volatile("" ::: "memory");   // pin LDS-sourced state in VGPRs

    const int b = 16*w + l;
    const float* xin = xg + b * (T_ * S_);
    float* llout = out + (size_t)b * T_ * U_ + u;

    const floatx4 z = {0.f, 0.f, 0.f, 0.f};

    // E via VALU: Ev[jt][r] = dot4(cBem[jt][r], x)
    auto emitE = [&](floatx4* Edst, const floatx4& xr) {
        #pragma unroll
        for (int jt = 0; jt < 4; ++jt) {
            #pragma unroll
            for (int r = 0; r < 4; ++r) {
                const floatx4 cb = cBem[jt][r];
                Edst[jt][r] = fmaf(cb.x, xr.x,
                              fmaf(cb.y, xr.y,
                              fmaf(cb.z, xr.z, cb.w * xr.w)));
            }
        }
    };

    floatx4 Ev[4];
    emitE(Ev, *(const floatx4*)xin);     // E_0

    floatx4 xvA[4], xvB[4];
    #pragma unroll
    for (int i = 0; i < 4; ++i)
        xvA[i] = *(const floatx4*)(xin + (1 + i) * S_);   // x_1..x_4 raw

    float hist[8];
    float ssf = 1.0f;
    float pp0 = 0.f, pa16 = 0.f, pa32 = 0.f, pa48 = 0.f;
    float Cacc = 0.f;
    float offacc = 0.f, sumk = 0.f;

    // consume step (slot kprev)'s shfl results: raw ss capture only.
    auto consume = [&](int kprev, bool o) {
        float ss = (pp0 + pa16) + (pa32 + pa48);
        hist[kprev] = o ? ss : hist[kprev];
        if (kprev == 5) ssf = ss;
    };

    // one HMM step. xr = raw x_{t+1}.
    auto step = [&](const floatx4& xr, int slot, bool own, bool ownP) {
        // gv_t = Ev_t o Rv_t   (raw/hat forward variable)
        floatx4 gv[4];
        #pragma unroll
        for (int jt = 0; jt < 4; ++jt) gv[jt] = Ev[jt] * Rv[jt];

        // pack b_t
        bf16x8 bf0, bf1;
        #pragma unroll
        for (int p = 0; p < 4; ++p) {
            bf0[p]     = (__bf16)gv[0][p];
            bf0[4 + p] = (__bf16)gv[1][p];
            bf1[p]     = (__bf16)gv[2][p];
            bf1[4 + p] = (__bf16)gv[3][p];
        }

        // R_{t+1} = A^T b_t (chained C accumulation) — the only 8 MFMAs
        #pragma unroll
        for (int jt = 0; jt < 4; ++jt) {
            floatx4 acc = __builtin_amdgcn_mfma_f32_16x16x32_bf16(afrag[jt][0], bf0, z, 0, 0, 0);
            Rv[jt] = __builtin_amdgcn_mfma_f32_16x16x32_bf16(afrag[jt][1], bf1, acc, 0, 0, 0);
        }

        // consume previous step's shfl results (after MFMA issue).
        // slot 0 consumes the previous octet's slot 7 (deferred).
        if (slot == 0) consume(7, ownP); else consume(slot - 1, own);

        // Ev_{t+1} = Bem . x_{t+1} on the VALU (fills MFMA-gap cycles)
        emitE(Ev, xr);

        // issue ss_t reduce last: in-lane adds + 3 parallel shfls
        floatx4 s4 = (gv[0] + gv[1]) + (gv[2] + gv[3]);
        pp0  = (s4.x + s4.y) + (s4.z + s4.w);
        pa16 = __shfl_xor(pp0, 16, 64);
        pa32 = __shfl_xor(pp0, 32, 64);
        pa48 = __shfl_xor(pp0, 48, 64);
    };

    // ---------------- T-loop: one octet per iteration ----------------
    #pragma unroll 1
    for (int tb = 0; tb < T_; tb += 8) {
        const int oct = (tb >> 3) & 3;
        const bool own  = (q == oct);
        const bool ownP = (q == ((oct + 3) & 3));

        #pragma unroll
        for (int i = 0; i < 4; ++i) {
            int ti = tb + 5 + i; ti = (ti < T_) ? ti : T_ - 1;
            xvB[i] = *(const floatx4*)(xin + ti * S_);
        }

        step(xvA[0], 0, own, ownP); step(xvA[1], 1, own, ownP);
        step(xvA[2], 2, own, ownP); step(xvA[3], 3, own, ownP);

        #pragma unroll
        for (int i = 0; i < 4; ++i) {
            int ti = tb + 9 + i; ti = (ti < T_) ? ti : T_ - 1;
            xvA[i] = *(const floatx4*)(xin + ti * S_);
        }

        step(xvB[0], 4, own, ownP); step(xvB[1], 5, own, ownP);
        step(xvB[2], 6, own, ownP); step(xvB[3], 7, own, ownP);

        if (oct == 3) consume(7, own);   // pre-flush tail (once per 32)

        // octet boundary: exact power-of-2 rescale of the hat-state.
        // f = 2^-k, k = unbiased exponent of ssraw_{slot5} (2-step slack).
        {
            unsigned eb = (__float_as_uint(ssf) >> 23) & 255u;
            float f = __uint_as_float((254u - eb) << 23);
            #pragma unroll
            for (int jt = 0; jt < 4; ++jt) Rv[jt] *= f;
            float kf = (float)((int)eb - 127);
            offacc += (q > oct) ? kf : 0.f;   // octets before lane q's octet
            sumk   += kf;
        }

        // ---------------- flush: ll_t = log(ssraw_t) + correction -------
        if (oct == 3) {
            float base = Cacc + LN2F * offacc;
            float* fp = llout + (size_t)(tb - 24 + 8 * q) * U_;
            #pragma unroll
            for (int k = 0; k < 8; ++k)
                fp[(size_t)k * U_] = __logf(hist[k]) + base;
            Cacc += LN2F * sumk;
            offacc = 0.f; sumk = 0.f;
        }
    }
}

extern "C" void kernel_launch(void* const* d_in, const int* in_sizes, int n_in,
                              void* d_out, int out_size, void* d_ws, size_t ws_size,
                              hipStream_t stream) {
    const float* xg    = (const float*)d_in[0];
    const float* trans = (const float*)d_in[1];
    const float* emis  = (const float*)d_in[2];
    const float* initk = (const float*)d_in[3];
    float* out = (float*)d_out;
    hipLaunchKernelGGL(hmm_fwd_kernel, dim3(U_), dim3(256), 0, stream,
                       xg, trans, emis, initk, out);
}

// Round 5
// 334.298 us; speedup vs baseline: 1.1412x; 1.0910x over previous
//
#include <hip/hip_runtime.h>

// HMM forward scan, one workgroup per unit u. U=256, N=64, S=4, B=64, T=1024.
// Wave w owns batches [16w,16w+16); lane (q=lane>>4,l=lane&15) owns batch
// b=16w+l and the 16 states j = sig(jt, 4q+r).
//
// R13: UNCHAINED MFMAs. Evidence R8/R11/R12: period pinned at ~780cy/step
// across 8/12/14-MFMA variants -> the invariant is the acc-chained MFMA
// pairs (mfma(af1,bf1, mfma(af0,bf0,z))). With in-order issue and 1
// wave/SIMD (1024 chains / 1024 SIMDs, fixed), each dependent MFMA stalls
// the issue port ~100cy with nothing to fill it; 4 serialized chains/step
// ~= the mystery 400cy. Fix: separate half-K accumulators, combined on
// the VALU one step LATER (lag-1, fully covered):
//   P0[jt]=mfma(afrag[jt][0],bf0,z); P1[jt]=mfma(afrag[jt][1],bf1,z);
//   next step: Rv = P0+P1.
// Same for ss (ssA[0]+ssB[0]). E via MFMA (min VALU). All 14 MFMAs/step
// mutually independent; every MFMA result is consumed lag-1.
// Octet pow2 rescale folded into slot-0's gv (gv *= fcur) -> no exposed
// wait on in-flight P regs at the boundary.
// Unnormalized recursion + exact pow2 octet rescale + once-per-32 flush
// as in R10 (proven).

#define U_ 256
#define N_ 64
#define S_ 4
#define B_ 64
#define T_ 1024
#define ROWP 72
#define LN2F 0.69314718055994530942f

typedef __attribute__((ext_vector_type(8))) __bf16 bf16x8;
typedef __attribute__((ext_vector_type(4))) float floatx4;

__device__ __forceinline__ int sig(int jt, int m) {
    return 32 * (jt >> 1) + 4 * (jt & 1) + 8 * (m >> 2) + (m & 3);
}

__launch_bounds__(256, 1)
__global__ void hmm_fwd_kernel(const float* __restrict__ xg,     // [B][T][S]
                               const float* __restrict__ trans,  // [U][N][N]
                               const float* __restrict__ emis,   // [U][N][S]
                               const float* __restrict__ initk,  // [U][N]
                               float* __restrict__ out)          // [B][T][U]
{
    __shared__ __bf16 AT[N_ * ROWP];
    __shared__ float BemS[N_][S_];
    __shared__ float IS[N_];

    const int bid = blockIdx.x;
    const int u = ((bid & 7) << 5) | (bid >> 3);   // XCD-aware u swizzle
    const int tid = threadIdx.x;
    const int lane = tid & 63;
    const int w = tid >> 6;
    const int q = lane >> 4;
    const int l = lane & 15;

    // ---------------- prologue: softmaxes (one-time) ----------------
    if (tid < 64) {
        const float* rowp = trans + (u * N_ + tid) * N_;
        float v[N_];
        #pragma unroll
        for (int k = 0; k < 16; ++k) {
            floatx4 t4 = *(const floatx4*)(rowp + 4 * k);
            v[4*k] = t4.x; v[4*k+1] = t4.y; v[4*k+2] = t4.z; v[4*k+3] = t4.w;
        }
        float m = v[0];
        #pragma unroll
        for (int j = 1; j < N_; ++j) m = fmaxf(m, v[j]);
        float s = 0.f;
        #pragma unroll
        for (int j = 0; j < N_; ++j) { v[j] = __expf(v[j] - m); s += v[j]; }
        float inv = 1.0f / s;
        #pragma unroll
        for (int j = 0; j < N_; ++j) AT[j * ROWP + tid] = (__bf16)(v[j] * inv);
    } else if (tid < 128) {
        int n = tid - 64;
        floatx4 e4 = *(const floatx4*)(emis + (u * N_ + n) * S_);
        float m = fmaxf(fmaxf(e4.x, e4.y), fmaxf(e4.z, e4.w));
        float a = __expf(e4.x - m), b2 = __expf(e4.y - m);
        float c = __expf(e4.z - m), d = __expf(e4.w - m);
        float inv = 1.0f / (a + b2 + c + d);
        BemS[n][0] = a*inv; BemS[n][1] = b2*inv; BemS[n][2] = c*inv; BemS[n][3] = d*inv;
    } else if (tid < 192) {
        int j = tid - 128;
        float v = initk[u * N_ + j];
        float m = v;
        #pragma unroll
        for (int s = 1; s < 64; s <<= 1) m = fmaxf(m, __shfl_xor(m, s, 64));
        float e = __expf(v - m);
        float ssum = e;
        #pragma unroll
        for (int s = 1; s < 64; s <<= 1) ssum += __shfl_xor(ssum, s, 64);
        IS[j] = e / ssum;
    }
    __syncthreads();

    // ------------- persistent register state -------------
    bf16x8 afrag[4][2];
    #pragma unroll
    for (int jt = 0; jt < 4; ++jt)
        #pragma unroll
        for (int kt = 0; kt < 2; ++kt)
            afrag[jt][kt] = *(const bf16x8*)&AT[sig(jt, l) * ROWP + 32*kt + 8*q];

    bf16x8 afragE[4];
    #pragma unroll
    for (int jt = 0; jt < 4; ++jt) {
        #pragma unroll
        for (int p = 0; p < 8; ++p) afragE[jt][p] = (__bf16)0.f;
        if (q == 0) {
            #pragma unroll
            for (int c = 0; c < 4; ++c)
                afragE[jt][c] = (__bf16)BemS[sig(jt, l)][c];
        }
    }

    bf16x8 onesf;
    #pragma unroll
    for (int p = 0; p < 8; ++p) onesf[p] = (__bf16)1.0f;

    // state: Rv(t) = P0[jt] + P1[jt] (combined lazily, lag-1)
    floatx4 P0[4], P1[4];
    #pragma unroll
    for (int jt = 0; jt < 4; ++jt)
        #pragma unroll
        for (int r = 0; r < 4; ++r) {
            P0[jt][r] = IS[sig(jt, 4*q + r)];
            P1[jt][r] = 0.f;
        }

    __asm__ volatile("" ::: "memory");   // pin LDS-sourced state in VGPRs

    const int b = 16*w + l;
    const float* xin = xg + b * (T_ * S_);
    float* llout = out + (size_t)b * T_ * U_ + u;

    const floatx4 z = {0.f, 0.f, 0.f, 0.f};
    floatx4 Ev[4];
    floatx4 ssvA = z, ssvB = z;          // prev step's half-sums (MFMA results)

    bf16x8 be;
    #pragma unroll
    for (int p = 0; p < 8; ++p) be[p] = (__bf16)0.f;   // hi half stays zero

    // ---------------- pipeline fill ----------------
    {
        floatx4 x0 = *(const floatx4*)xin;
        be[0] = (__bf16)x0.x; be[1] = (__bf16)x0.y;
        be[2] = (__bf16)x0.z; be[3] = (__bf16)x0.w;
        #pragma unroll
        for (int jt = 0; jt < 4; ++jt)
            Ev[jt] = __builtin_amdgcn_mfma_f32_16x16x32_bf16(afragE[jt], be, z, 0, 0, 0);
    }
    floatx4 xvA[4], xvB[4];
    #pragma unroll
    for (int i = 0; i < 4; ++i)
        xvA[i] = *(const floatx4*)(xin + (1 + i) * S_);   // x_1..x_4 raw

    float hist[8];
    float ssf = 1.0f;
    float fcur = 1.0f;                   // pow2 rescale, applied at slot 0
    float Cacc = 0.f;
    float offacc = 0.f, sumk = 0.f;

    // one HMM step. xr = raw x_{t+1}. fsc = 1.0 except slot 0 (octet rescale).
    auto step = [&](const floatx4& xr, int slot, bool own, bool ownP, float fsc) {
        // ---------- V phase ----------
        // Rv = P0+P1 (oldest MFMA results first), then gv = Ev o Rv * fsc
        floatx4 Rv[4];
        #pragma unroll
        for (int jt = 0; jt < 4; ++jt) Rv[jt] = P0[jt] + P1[jt];

        // capture previous step's ss (half-sums combined on VALU)
        {
            float ssp = ssvA[0] + ssvB[0];
            if (slot == 0) {
                hist[7] = ownP ? ssp : hist[7];
            } else {
                hist[slot - 1] = own ? ssp : hist[slot - 1];
                if (slot == 6) ssf = ssp;   // slot-5 ss, 2 steps of slack
            }
        }

        // be: only low 4 elems change (hi half constant zero)
        be[0] = (__bf16)xr.x; be[1] = (__bf16)xr.y;
        be[2] = (__bf16)xr.z; be[3] = (__bf16)xr.w;

        floatx4 gv[4];
        #pragma unroll
        for (int jt = 0; jt < 4; ++jt) gv[jt] = (Ev[jt] * Rv[jt]) * fsc;

        // pack b_t
        bf16x8 bf0, bf1;
        #pragma unroll
        for (int p = 0; p < 4; ++p) {
            bf0[p]     = (__bf16)gv[0][p];
            bf0[4 + p] = (__bf16)gv[1][p];
            bf1[p]     = (__bf16)gv[2][p];
            bf1[4 + p] = (__bf16)gv[3][p];
        }

        // ---------- M phase: 14 mutually independent MFMAs ----------
        #pragma unroll
        for (int jt = 0; jt < 4; ++jt)
            P0[jt] = __builtin_amdgcn_mfma_f32_16x16x32_bf16(afrag[jt][0], bf0, z, 0, 0, 0);
        #pragma unroll
        for (int jt = 0; jt < 4; ++jt)
            P1[jt] = __builtin_amdgcn_mfma_f32_16x16x32_bf16(afrag[jt][1], bf1, z, 0, 0, 0);
        ssvA = __builtin_amdgcn_mfma_f32_16x16x32_bf16(onesf, bf0, z, 0, 0, 0);
        ssvB = __builtin_amdgcn_mfma_f32_16x16x32_bf16(onesf, bf1, z, 0, 0, 0);
        #pragma unroll
        for (int jt = 0; jt < 4; ++jt)
            Ev[jt] = __builtin_amdgcn_mfma_f32_16x16x32_bf16(afragE[jt], be, z, 0, 0, 0);
    };

    // ---------------- T-loop: one octet per iteration ----------------
    #pragma unroll 1
    for (int tb = 0; tb < T_; tb += 8) {
        const int oct = (tb >> 3) & 3;
        const bool own  = (q == oct);
        const bool ownP = (q == ((oct + 3) & 3));

        #pragma unroll
        for (int i = 0; i < 4; ++i) {
            int ti = tb + 5 + i; ti = (ti < T_) ? ti : T_ - 1;
            xvB[i] = *(const floatx4*)(xin + ti * S_);
        }

        step(xvA[0], 0, own, ownP, fcur);
        step(xvA[1], 1, own, ownP, 1.0f);
        step(xvA[2], 2, own, ownP, 1.0f);
        step(xvA[3], 3, own, ownP, 1.0f);

        #pragma unroll
        for (int i = 0; i < 4; ++i) {
            int ti = tb + 9 + i; ti = (ti < T_) ? ti : T_ - 1;
            xvA[i] = *(const floatx4*)(xin + ti * S_);
        }

        step(xvB[0], 4, own, ownP, 1.0f);
        step(xvB[1], 5, own, ownP, 1.0f);
        step(xvB[2], 6, own, ownP, 1.0f);
        step(xvB[3], 7, own, ownP, 1.0f);

        if (oct == 3) {   // pre-flush tail capture of slot 7 (once per 32)
            float ssp = ssvA[0] + ssvB[0];
            hist[7] = own ? ssp : hist[7];
        }

        // octet boundary: derive next pow2 rescale from ssraw_{slot5}.
        // Applied at next octet's slot 0 via gv *= fcur (no exposed wait
        // on in-flight P regs).
        {
            unsigned eb = (__float_as_uint(ssf) >> 23) & 255u;
            fcur = __uint_as_float((254u - eb) << 23);
            float kf = (float)((int)eb - 127);
            offacc += (q > oct) ? kf : 0.f;   // octets before lane q's octet
            sumk   += kf;
        }

        // ---------------- flush: ll_t = log(ssraw_t) + correction -------
        if (oct == 3) {
            float base = Cacc + LN2F * offacc;
            float* fp = llout + (size_t)(tb - 24 + 8 * q) * U_;
            #pragma unroll
            for (int k = 0; k < 8; ++k)
                fp[(size_t)k * U_] = __logf(hist[k]) + base;
            Cacc += LN2F * sumk;
            offacc = 0.f; sumk = 0.f;
        }
    }
}

extern "C" void kernel_launch(void* const* d_in, const int* in_sizes, int n_in,
                              void* d_out, int out_size, void* d_ws, size_t ws_size,
                              hipStream_t stream) {
    const float* xg    = (const float*)d_in[0];
    const float* trans = (const float*)d_in[1];
    const float* emis  = (const float*)d_in[2];
    const float* initk = (const float*)d_in[3];
    float* out = (float*)d_out;
    hipLaunchKernelGGL(hmm_fwd_kernel, dim3(U_), dim3(256), 0, stream,
                       xg, trans, emis, initk, out);
}